// Round 10
// baseline (116.023 us; speedup 1.0000x reference)
//
#include <hip/hip_runtime.h>

// GaborBasis: out[b,t,r] = window_norm * cos(z·K[r] + phi[r]),
//   window = exp(-max(|z|^2+|mu_r|^2-2 z·mu_r,0)/(2 sigma_r^2)), normalized over r.
// fp16 hi/lo 3-term split MFMA (16x16x32); hw-cos epilogue.
// Round 10: per-CU VMEM was the tallest pipe (B fragments re-read per block:
// 4MB/CU > MFMA 24.8us). Block = 64 rows x 1024 cols, 1024 thr (16 waves),
// grid 256 = 1 block/CU -> B traffic/CU halves to 2MB. Epilogue cos via
// v_fract+v_cos (phase already in revolutions): ~9 VALU/elem vs ~19.

typedef _Float16 f16x8 __attribute__((ext_vector_type(8)));
typedef float f32x4 __attribute__((ext_vector_type(4)));

#define M_DIM 16384
#define R_DIM 1024
#define INV2PI 0.15915494309189535f

// ---------------- prep: z_sq[16384], mu_sq[1024], inv2s2[1024], phirev[1024] ----------------
__global__ void gabor_prep(const float* __restrict__ z, const float* __restrict__ mu,
                           const float* __restrict__ ls, const float* __restrict__ phi,
                           float* __restrict__ zsq, float* __restrict__ musq,
                           float* __restrict__ inv2s2, float* __restrict__ phirev) {
    const int lane = threadIdx.x & 63;
    const int wv = threadIdx.x >> 6;
    const int bid = blockIdx.x;
    if (bid < 4096) {
        const int row = bid * 4 + wv;
        float4 v = *(const float4*)(z + (size_t)row * 256 + lane * 4);
        float s = v.x * v.x + v.y * v.y + v.z * v.z + v.w * v.w;
#pragma unroll
        for (int sh = 1; sh < 64; sh <<= 1) s += __shfl_xor(s, sh, 64);
        if (lane == 0) zsq[row] = s;
    } else {
        const int row = (bid - 4096) * 4 + wv;
        float4 v = *(const float4*)(mu + (size_t)row * 256 + lane * 4);
        float s = v.x * v.x + v.y * v.y + v.z * v.z + v.w * v.w;
#pragma unroll
        for (int sh = 1; sh < 64; sh <<= 1) s += __shfl_xor(s, sh, 64);
        if (lane == 0) {
            musq[row] = s;
            float e = expf(ls[row]);
            inv2s2[row] = 1.0f / (2.0f * (e * e + 1e-8f));
            phirev[row] = phi[row] * INV2PI;
        }
    }
}

// ---------------- split: fp32 -> fp16 hi/lo in MFMA-fragment order ----------------
// Layout per matrix: [sub = row/16][ks = k/32][1024 halves]: hi at lane*8, lo at 512+lane*8,
// lane = (row&15) | ((k>>3 & 3)<<4). One thread = one (sub,ks,lane) = 8 fp32.
__global__ void gabor_split(const float* __restrict__ z, const float* __restrict__ mu,
                            const float* __restrict__ Kmat,
                            _Float16* __restrict__ zf, _Float16* __restrict__ muf,
                            _Float16* __restrict__ kf) {
    const int t = blockIdx.x * 256 + threadIdx.x;   // 0..589823
    const float* src; _Float16* dst; int item;
    if (t < 524288)      { item = t;          src = z;    dst = zf; }
    else if (t < 557056) { item = t - 524288; src = mu;   dst = muf; }
    else                 { item = t - 557056; src = Kmat; dst = kf; }
    const int sub = item >> 9, rem = item & 511;
    const int ks = rem >> 6, l = rem & 63;
    const int row = sub * 16 + (l & 15);
    const int k0 = ks * 32 + (l >> 4) * 8;
    const float* sp = src + (size_t)row * 256 + k0;
    float v[8];
    *(float4*)&v[0] = *(const float4*)(sp);
    *(float4*)&v[4] = *(const float4*)(sp + 4);
    f16x8 hi, lo;
#pragma unroll
    for (int j = 0; j < 8; ++j) {
        _Float16 h = (_Float16)v[j];
        hi[j] = h;
        lo[j] = (_Float16)(v[j] - (float)h);
    }
    _Float16* d = dst + (size_t)(sub * 8 + ks) * 1024;
    *(f16x8*)(d + l * 8) = hi;
    *(f16x8*)(d + 512 + l * 8) = lo;
}

// ---------------- main: 256 blocks x 1024 thr (16 waves). Block = 64 rows x 1024 cols. ----------------
// Wave = 32 rows x 32 cols per chunk; 4 chunks of 256 cols. Barrier-free K loop.
template <bool PRE>
__global__ __launch_bounds__(1024, 4) void gabor_main(
    const float* __restrict__ z, const float* __restrict__ mu, const float* __restrict__ Kmat,
    const _Float16* __restrict__ zf, const _Float16* __restrict__ muf, const _Float16* __restrict__ kf,
    const float* __restrict__ zsq, const float* __restrict__ musq,
    const float* __restrict__ inv2s2, const float* __restrict__ phirev,
    float* __restrict__ out) {
    __shared__ _Float16 sA[32768];      // [sub 0..3][ks 0..7][1024]: hi lane*8, lo 512+lane*8 (64KB)
    __shared__ float sZsq[64];
    __shared__ float sRow[8][64];
    __shared__ float sInvN[64];

    const int tid = threadIdx.x;
    const int bid = blockIdx.x;
    const int rbase = bid * 64;

    // ---- stage A panel (64 rows x 256 k, hi/lo) ONCE ----
    if constexpr (PRE) {
        const _Float16* zsrc = zf + (size_t)(bid * 4 * 8) * 1024;   // sub = rbase/16
#pragma unroll
        for (int j = 0; j < 4; ++j) {
            const int o = (j * 1024 + tid) * 8;                     // 16B units, coalesced
            *(f16x8*)&sA[o] = *(const f16x8*)(zsrc + o);
        }
    } else {
#pragma unroll
        for (int j = 0; j < 2; ++j) {
            const int it = tid + j * 1024;                           // 0..2047
            const int sub = it >> 9, rem = it & 511;
            const int ks = rem >> 6, l = rem & 63;
            const int row = rbase + sub * 16 + (l & 15);
            const float* sp = z + (size_t)row * 256 + ks * 32 + (l >> 4) * 8;
            float v[8];
            *(float4*)&v[0] = *(const float4*)(sp);
            *(float4*)&v[4] = *(const float4*)(sp + 4);
            f16x8 hi, lo;
#pragma unroll
            for (int q = 0; q < 8; ++q) {
                _Float16 h = (_Float16)v[q];
                hi[q] = h; lo[q] = (_Float16)(v[q] - (float)h);
            }
            const int o = (sub * 8 + ks) * 1024 + l * 8;
            *(f16x8*)&sA[o] = hi;
            *(f16x8*)&sA[o + 512] = lo;
        }
    }
    if (tid < 64) sZsq[tid] = zsq[rbase + tid];
    __syncthreads();                       // the ONLY barrier before the tail

    const int lane = tid & 63;
    const int wv = tid >> 6;               // 0..15
    const int wr = wv >> 3;                // 0..1  (row half: 32 rows)
    const int wc = wv & 7;                 // 0..7  (32-col slot within a 256-col chunk)
    const int lr = lane & 15, lg = lane >> 4;

    float rs[8];
#pragma unroll
    for (int i = 0; i < 8; ++i) rs[i] = 0.f;

    // B register sets: [mu0H, mu0L, mu1H, mu1L, k0H, k0L, k1H, k1L] x2 (ping-pong)
    f16x8 B[2][8];
    auto loadB = [&](int buf, int c, int ks) {
        if constexpr (PRE) {
            const size_t sb = (size_t)((c * 16 + wc * 2) * 8 + ks) * 1024 + lane * 8;
            const _Float16* mp = muf + sb;
            B[buf][0] = *(const f16x8*)(mp);
            B[buf][1] = *(const f16x8*)(mp + 512);
            B[buf][2] = *(const f16x8*)(mp + 8192);
            B[buf][3] = *(const f16x8*)(mp + 8192 + 512);
            const _Float16* kp = kf + sb;
            B[buf][4] = *(const f16x8*)(kp);
            B[buf][5] = *(const f16x8*)(kp + 512);
            B[buf][6] = *(const f16x8*)(kp + 8192);
            B[buf][7] = *(const f16x8*)(kp + 8192 + 512);
        } else {
#pragma unroll
            for (int n = 0; n < 2; ++n) {
                const int col = c * 256 + wc * 32 + n * 16 + lr;
                const int k0 = ks * 32 + lg * 8;
                float v[8];
                const float* sp = mu + (size_t)col * 256 + k0;
                *(float4*)&v[0] = *(const float4*)(sp);
                *(float4*)&v[4] = *(const float4*)(sp + 4);
#pragma unroll
                for (int q = 0; q < 8; ++q) {
                    _Float16 h = (_Float16)v[q];
                    B[buf][n * 2][q] = h; B[buf][n * 2 + 1][q] = (_Float16)(v[q] - (float)h);
                }
                const float* sp2 = Kmat + (size_t)col * 256 + k0;
                *(float4*)&v[0] = *(const float4*)(sp2);
                *(float4*)&v[4] = *(const float4*)(sp2 + 4);
#pragma unroll
                for (int q = 0; q < 8; ++q) {
                    _Float16 h = (_Float16)v[q];
                    B[buf][4 + n * 2][q] = h; B[buf][4 + n * 2 + 1][q] = (_Float16)(v[q] - (float)h);
                }
            }
        }
    };

    loadB(0, 0, 0);

#pragma unroll 1
    for (int c = 0; c < 4; ++c) {
        f32x4 accC[2][2], accP[2][2];
#pragma unroll
        for (int m = 0; m < 2; ++m)
#pragma unroll
            for (int n = 0; n < 2; ++n) {
                accC[m][n] = (f32x4){0.f, 0.f, 0.f, 0.f};
                accP[m][n] = (f32x4){0.f, 0.f, 0.f, 0.f};
            }

#pragma unroll
        for (int ks = 0; ks < 8; ++ks) {
            const int cur = ks & 1;
            const int nxt = cur ^ 1;        // at ks=7, slot 0 = next chunk's ks=0
            // A fragments from LDS (lane-linear, conflict-free)
            f16x8 aH[2], aL[2];
#pragma unroll
            for (int m = 0; m < 2; ++m) {
                const int o = ((wr * 2 + m) * 8 + ks) * 1024 + lane * 8;
                aH[m] = *(const f16x8*)&sA[o];
                aL[m] = *(const f16x8*)&sA[o + 512];
            }
            // rolling prefetch, pinned above the MFMA cluster
            if (ks < 7) loadB(nxt, c, ks + 1);
            else if (c < 3) loadB(0, c + 1, 0);   // covered by the chunk epilogue
            __builtin_amdgcn_sched_barrier(0);

            __builtin_amdgcn_s_setprio(1);
            // term-major: 4 independent acc chains between dependent reuses
#pragma unroll
            for (int m = 0; m < 2; ++m)
#pragma unroll
                for (int n = 0; n < 2; ++n)
                    accC[m][n] = __builtin_amdgcn_mfma_f32_16x16x32_f16(aH[m], B[cur][n * 2], accC[m][n], 0, 0, 0);
#pragma unroll
            for (int m = 0; m < 2; ++m)
#pragma unroll
                for (int n = 0; n < 2; ++n)
                    accC[m][n] = __builtin_amdgcn_mfma_f32_16x16x32_f16(aH[m], B[cur][n * 2 + 1], accC[m][n], 0, 0, 0);
#pragma unroll
            for (int m = 0; m < 2; ++m)
#pragma unroll
                for (int n = 0; n < 2; ++n)
                    accC[m][n] = __builtin_amdgcn_mfma_f32_16x16x32_f16(aL[m], B[cur][n * 2], accC[m][n], 0, 0, 0);
#pragma unroll
            for (int m = 0; m < 2; ++m)
#pragma unroll
                for (int n = 0; n < 2; ++n)
                    accP[m][n] = __builtin_amdgcn_mfma_f32_16x16x32_f16(aH[m], B[cur][4 + n * 2], accP[m][n], 0, 0, 0);
#pragma unroll
            for (int m = 0; m < 2; ++m)
#pragma unroll
                for (int n = 0; n < 2; ++n)
                    accP[m][n] = __builtin_amdgcn_mfma_f32_16x16x32_f16(aH[m], B[cur][4 + n * 2 + 1], accP[m][n], 0, 0, 0);
#pragma unroll
            for (int m = 0; m < 2; ++m)
#pragma unroll
                for (int n = 0; n < 2; ++n)
                    accP[m][n] = __builtin_amdgcn_mfma_f32_16x16x32_f16(aL[m], B[cur][4 + n * 2], accP[m][n], 0, 0, 0);
            __builtin_amdgcn_s_setprio(0);
        }

        // ---- per-chunk epilogue: w = __expf, cos via v_fract+v_cos (revolutions) ----
        // (also hides the (c+1, ks=0) B prefetch issued above)
#pragma unroll
        for (int m = 0; m < 2; ++m)
#pragma unroll
            for (int n = 0; n < 2; ++n) {
                const int col = c * 256 + wc * 32 + n * 16 + lr;
                const float msq = musq[col], il2 = inv2s2[col], prv = phirev[col];
                f32x4 cc = accC[m][n], pp = accP[m][n];
#pragma unroll
                for (int rg = 0; rg < 4; ++rg) {
                    const int rowl = wr * 32 + m * 16 + lg * 4 + rg;
                    float dsq = fmaxf(sZsq[rowl] + msq - 2.0f * cc[rg], 0.f);
                    float w = __expf(-dsq * il2);
                    float ph = __builtin_fmaf(pp[rg], INV2PI, prv);
                    float r, cs;
                    asm("v_fract_f32 %0, %1" : "=v"(r) : "v"(ph));
                    asm("v_cos_f32 %0, %1" : "=v"(cs) : "v"(r));
                    out[(size_t)(rbase + rowl) * R_DIM + col] = w * cs;
                    rs[m * 4 + rg] += w;
                }
            }
    }

    // ---- block-local row sums -> normalize own 64x1024 tile ----
#pragma unroll
    for (int i = 0; i < 8; ++i) {
#pragma unroll
        for (int sh = 1; sh < 16; sh <<= 1) rs[i] += __shfl_xor(rs[i], sh, 64);
    }
    if (lr == 0) {
#pragma unroll
        for (int m = 0; m < 2; ++m)
#pragma unroll
            for (int rg = 0; rg < 4; ++rg)
                sRow[wc][wr * 32 + m * 16 + lg * 4 + rg] = rs[m * 4 + rg];
    }
    __syncthreads();
    if (tid < 64) {
        float s = 0.f;
#pragma unroll
        for (int w8 = 0; w8 < 8; ++w8) s += sRow[w8][tid];
        sInvN[tid] = 1.0f / fmaxf(s, 1e-6f);
    }
    __threadfence_block();
    __syncthreads();

    float4* obase = (float4*)(out + (size_t)rbase * R_DIM);
#pragma unroll 4
    for (int j = 0; j < 16; ++j) {
        const int idx = j * 1024 + tid;       // 0..16383 float4s
        const int row = idx >> 8, c4 = idx & 255;
        const float inv = sInvN[row];
        float4 v = obase[row * 256 + c4];
        v.x *= inv; v.y *= inv; v.z *= inv; v.w *= inv;
        obase[row * 256 + c4] = v;
    }
}

extern "C" void kernel_launch(void* const* d_in, const int* in_sizes, int n_in,
                              void* d_out, int out_size, void* d_ws, size_t ws_size,
                              hipStream_t stream) {
    const float* z    = (const float*)d_in[0];
    const float* mu   = (const float*)d_in[1];
    const float* Kmat = (const float*)d_in[2];
    const float* ls   = (const float*)d_in[3];
    const float* phi  = (const float*)d_in[4];
    float* out = (float*)d_out;
    float* ws = (float*)d_ws;
    float* zsq      = ws;                        // 16384
    float* musq     = ws + 16384;                // 1024
    float* i2s      = ws + 17408;                // 1024
    float* phirev   = ws + 18432;                // 1024
    _Float16* zf  = (_Float16*)(ws + 150528);    // 16384*512 halves (fragment order)
    _Float16* muf = zf + 8388608;                // 1024*512
    _Float16* kf  = muf + 524288;                // 1024*512
    const bool pre = ws_size >= 19476480ull;

    hipLaunchKernelGGL(gabor_prep, dim3(4096 + 256), dim3(256), 0, stream,
                       z, mu, ls, phi, zsq, musq, i2s, phirev);
    if (pre) {
        hipLaunchKernelGGL(gabor_split, dim3(2304), dim3(256), 0, stream,
                           z, mu, Kmat, zf, muf, kf);
        hipLaunchKernelGGL(gabor_main<true>, dim3(M_DIM / 64), dim3(1024), 0, stream,
                           z, mu, Kmat, zf, muf, kf, zsq, musq, i2s, phirev, out);
    } else {
        hipLaunchKernelGGL(gabor_main<false>, dim3(M_DIM / 64), dim3(1024), 0, stream,
                           z, mu, Kmat, zf, muf, kf, zsq, musq, i2s, phirev, out);
    }
}

// Round 11
// 115.378 us; speedup vs baseline: 1.0056x; 1.0056x over previous
//
#include <hip/hip_runtime.h>

// GaborBasis: out[b,t,r] = window_norm * cos(z·K[r] + phi[r]),
//   window = exp(-max(|z|^2+|mu_r|^2-2 z·mu_r,0)/(2 sigma_r^2)), normalized over r.
// fp16 hi/lo 3-term split MFMA (16x16x32); hw-cos epilogue.
// Round 10: per-CU VMEM was the tallest pipe (B fragments re-read per block:
// 4MB/CU > MFMA 24.8us). Block = 64 rows x 1024 cols, 1024 thr (16 waves),
// grid 256 = 1 block/CU -> B traffic/CU halves to 2MB. Epilogue cos via
// v_fract+v_cos (phase already in revolutions): ~9 VALU/elem vs ~19.

typedef _Float16 f16x8 __attribute__((ext_vector_type(8)));
typedef float f32x4 __attribute__((ext_vector_type(4)));

#define M_DIM 16384
#define R_DIM 1024
#define INV2PI 0.15915494309189535f

// ---------------- prep: z_sq[16384], mu_sq[1024], inv2s2[1024], phirev[1024] ----------------
__global__ void gabor_prep(const float* __restrict__ z, const float* __restrict__ mu,
                           const float* __restrict__ ls, const float* __restrict__ phi,
                           float* __restrict__ zsq, float* __restrict__ musq,
                           float* __restrict__ inv2s2, float* __restrict__ phirev) {
    const int lane = threadIdx.x & 63;
    const int wv = threadIdx.x >> 6;
    const int bid = blockIdx.x;
    if (bid < 4096) {
        const int row = bid * 4 + wv;
        float4 v = *(const float4*)(z + (size_t)row * 256 + lane * 4);
        float s = v.x * v.x + v.y * v.y + v.z * v.z + v.w * v.w;
#pragma unroll
        for (int sh = 1; sh < 64; sh <<= 1) s += __shfl_xor(s, sh, 64);
        if (lane == 0) zsq[row] = s;
    } else {
        const int row = (bid - 4096) * 4 + wv;
        float4 v = *(const float4*)(mu + (size_t)row * 256 + lane * 4);
        float s = v.x * v.x + v.y * v.y + v.z * v.z + v.w * v.w;
#pragma unroll
        for (int sh = 1; sh < 64; sh <<= 1) s += __shfl_xor(s, sh, 64);
        if (lane == 0) {
            musq[row] = s;
            float e = expf(ls[row]);
            inv2s2[row] = 1.0f / (2.0f * (e * e + 1e-8f));
            phirev[row] = phi[row] * INV2PI;
        }
    }
}

// ---------------- split: fp32 -> fp16 hi/lo in MFMA-fragment order ----------------
// Layout per matrix: [sub = row/16][ks = k/32][1024 halves]: hi at lane*8, lo at 512+lane*8,
// lane = (row&15) | ((k>>3 & 3)<<4). One thread = one (sub,ks,lane) = 8 fp32.
__global__ void gabor_split(const float* __restrict__ z, const float* __restrict__ mu,
                            const float* __restrict__ Kmat,
                            _Float16* __restrict__ zf, _Float16* __restrict__ muf,
                            _Float16* __restrict__ kf) {
    const int t = blockIdx.x * 256 + threadIdx.x;   // 0..589823
    const float* src; _Float16* dst; int item;
    if (t < 524288)      { item = t;          src = z;    dst = zf; }
    else if (t < 557056) { item = t - 524288; src = mu;   dst = muf; }
    else                 { item = t - 557056; src = Kmat; dst = kf; }
    const int sub = item >> 9, rem = item & 511;
    const int ks = rem >> 6, l = rem & 63;
    const int row = sub * 16 + (l & 15);
    const int k0 = ks * 32 + (l >> 4) * 8;
    const float* sp = src + (size_t)row * 256 + k0;
    float v[8];
    *(float4*)&v[0] = *(const float4*)(sp);
    *(float4*)&v[4] = *(const float4*)(sp + 4);
    f16x8 hi, lo;
#pragma unroll
    for (int j = 0; j < 8; ++j) {
        _Float16 h = (_Float16)v[j];
        hi[j] = h;
        lo[j] = (_Float16)(v[j] - (float)h);
    }
    _Float16* d = dst + (size_t)(sub * 8 + ks) * 1024;
    *(f16x8*)(d + l * 8) = hi;
    *(f16x8*)(d + 512 + l * 8) = lo;
}

// ---------------- main: 256 blocks x 1024 thr (16 waves). Block = 64 rows x 1024 cols. ----------------
// Wave = 32 rows x 32 cols per chunk; 4 chunks of 256 cols. Barrier-free K loop.
template <bool PRE>
__global__ __launch_bounds__(1024, 4) void gabor_main(
    const float* __restrict__ z, const float* __restrict__ mu, const float* __restrict__ Kmat,
    const _Float16* __restrict__ zf, const _Float16* __restrict__ muf, const _Float16* __restrict__ kf,
    const float* __restrict__ zsq, const float* __restrict__ musq,
    const float* __restrict__ inv2s2, const float* __restrict__ phirev,
    float* __restrict__ out) {
    __shared__ _Float16 sA[32768];      // [sub 0..3][ks 0..7][1024]: hi lane*8, lo 512+lane*8 (64KB)
    __shared__ float sZsq[64];
    __shared__ float sRow[8][64];
    __shared__ float sInvN[64];

    const int tid = threadIdx.x;
    const int bid = blockIdx.x;
    const int rbase = bid * 64;

    // ---- stage A panel (64 rows x 256 k, hi/lo) ONCE ----
    if constexpr (PRE) {
        const _Float16* zsrc = zf + (size_t)(bid * 4 * 8) * 1024;   // sub = rbase/16
#pragma unroll
        for (int j = 0; j < 4; ++j) {
            const int o = (j * 1024 + tid) * 8;                     // 16B units, coalesced
            *(f16x8*)&sA[o] = *(const f16x8*)(zsrc + o);
        }
    } else {
#pragma unroll
        for (int j = 0; j < 2; ++j) {
            const int it = tid + j * 1024;                           // 0..2047
            const int sub = it >> 9, rem = it & 511;
            const int ks = rem >> 6, l = rem & 63;
            const int row = rbase + sub * 16 + (l & 15);
            const float* sp = z + (size_t)row * 256 + ks * 32 + (l >> 4) * 8;
            float v[8];
            *(float4*)&v[0] = *(const float4*)(sp);
            *(float4*)&v[4] = *(const float4*)(sp + 4);
            f16x8 hi, lo;
#pragma unroll
            for (int q = 0; q < 8; ++q) {
                _Float16 h = (_Float16)v[q];
                hi[q] = h; lo[q] = (_Float16)(v[q] - (float)h);
            }
            const int o = (sub * 8 + ks) * 1024 + l * 8;
            *(f16x8*)&sA[o] = hi;
            *(f16x8*)&sA[o + 512] = lo;
        }
    }
    if (tid < 64) sZsq[tid] = zsq[rbase + tid];
    __syncthreads();                       // the ONLY barrier before the tail

    const int lane = tid & 63;
    const int wv = tid >> 6;               // 0..15
    const int wr = wv >> 3;                // 0..1  (row half: 32 rows)
    const int wc = wv & 7;                 // 0..7  (32-col slot within a 256-col chunk)
    const int lr = lane & 15, lg = lane >> 4;

    float rs[8];
#pragma unroll
    for (int i = 0; i < 8; ++i) rs[i] = 0.f;

    // B register sets: [mu0H, mu0L, mu1H, mu1L, k0H, k0L, k1H, k1L] x2 (ping-pong)
    f16x8 B[2][8];
    auto loadB = [&](int buf, int c, int ks) {
        if constexpr (PRE) {
            const size_t sb = (size_t)((c * 16 + wc * 2) * 8 + ks) * 1024 + lane * 8;
            const _Float16* mp = muf + sb;
            B[buf][0] = *(const f16x8*)(mp);
            B[buf][1] = *(const f16x8*)(mp + 512);
            B[buf][2] = *(const f16x8*)(mp + 8192);
            B[buf][3] = *(const f16x8*)(mp + 8192 + 512);
            const _Float16* kp = kf + sb;
            B[buf][4] = *(const f16x8*)(kp);
            B[buf][5] = *(const f16x8*)(kp + 512);
            B[buf][6] = *(const f16x8*)(kp + 8192);
            B[buf][7] = *(const f16x8*)(kp + 8192 + 512);
        } else {
#pragma unroll
            for (int n = 0; n < 2; ++n) {
                const int col = c * 256 + wc * 32 + n * 16 + lr;
                const int k0 = ks * 32 + lg * 8;
                float v[8];
                const float* sp = mu + (size_t)col * 256 + k0;
                *(float4*)&v[0] = *(const float4*)(sp);
                *(float4*)&v[4] = *(const float4*)(sp + 4);
#pragma unroll
                for (int q = 0; q < 8; ++q) {
                    _Float16 h = (_Float16)v[q];
                    B[buf][n * 2][q] = h; B[buf][n * 2 + 1][q] = (_Float16)(v[q] - (float)h);
                }
                const float* sp2 = Kmat + (size_t)col * 256 + k0;
                *(float4*)&v[0] = *(const float4*)(sp2);
                *(float4*)&v[4] = *(const float4*)(sp2 + 4);
#pragma unroll
                for (int q = 0; q < 8; ++q) {
                    _Float16 h = (_Float16)v[q];
                    B[buf][4 + n * 2][q] = h; B[buf][4 + n * 2 + 1][q] = (_Float16)(v[q] - (float)h);
                }
            }
        }
    };

    loadB(0, 0, 0);

#pragma unroll 1
    for (int c = 0; c < 4; ++c) {
        f32x4 accC[2][2], accP[2][2];
#pragma unroll
        for (int m = 0; m < 2; ++m)
#pragma unroll
            for (int n = 0; n < 2; ++n) {
                accC[m][n] = (f32x4){0.f, 0.f, 0.f, 0.f};
                accP[m][n] = (f32x4){0.f, 0.f, 0.f, 0.f};
            }

#pragma unroll
        for (int ks = 0; ks < 8; ++ks) {
            const int cur = ks & 1;
            const int nxt = cur ^ 1;        // at ks=7, slot 0 = next chunk's ks=0
            // A fragments from LDS (lane-linear, conflict-free)
            f16x8 aH[2], aL[2];
#pragma unroll
            for (int m = 0; m < 2; ++m) {
                const int o = ((wr * 2 + m) * 8 + ks) * 1024 + lane * 8;
                aH[m] = *(const f16x8*)&sA[o];
                aL[m] = *(const f16x8*)&sA[o + 512];
            }
            // rolling prefetch, pinned above the MFMA cluster
            if (ks < 7) loadB(nxt, c, ks + 1);
            else if (c < 3) loadB(0, c + 1, 0);   // covered by the chunk epilogue
            __builtin_amdgcn_sched_barrier(0);

            __builtin_amdgcn_s_setprio(1);
            // term-major: 4 independent acc chains between dependent reuses
#pragma unroll
            for (int m = 0; m < 2; ++m)
#pragma unroll
                for (int n = 0; n < 2; ++n)
                    accC[m][n] = __builtin_amdgcn_mfma_f32_16x16x32_f16(aH[m], B[cur][n * 2], accC[m][n], 0, 0, 0);
#pragma unroll
            for (int m = 0; m < 2; ++m)
#pragma unroll
                for (int n = 0; n < 2; ++n)
                    accC[m][n] = __builtin_amdgcn_mfma_f32_16x16x32_f16(aH[m], B[cur][n * 2 + 1], accC[m][n], 0, 0, 0);
#pragma unroll
            for (int m = 0; m < 2; ++m)
#pragma unroll
                for (int n = 0; n < 2; ++n)
                    accC[m][n] = __builtin_amdgcn_mfma_f32_16x16x32_f16(aL[m], B[cur][n * 2], accC[m][n], 0, 0, 0);
#pragma unroll
            for (int m = 0; m < 2; ++m)
#pragma unroll
                for (int n = 0; n < 2; ++n)
                    accP[m][n] = __builtin_amdgcn_mfma_f32_16x16x32_f16(aH[m], B[cur][4 + n * 2], accP[m][n], 0, 0, 0);
#pragma unroll
            for (int m = 0; m < 2; ++m)
#pragma unroll
                for (int n = 0; n < 2; ++n)
                    accP[m][n] = __builtin_amdgcn_mfma_f32_16x16x32_f16(aH[m], B[cur][4 + n * 2 + 1], accP[m][n], 0, 0, 0);
#pragma unroll
            for (int m = 0; m < 2; ++m)
#pragma unroll
                for (int n = 0; n < 2; ++n)
                    accP[m][n] = __builtin_amdgcn_mfma_f32_16x16x32_f16(aL[m], B[cur][4 + n * 2], accP[m][n], 0, 0, 0);
            __builtin_amdgcn_s_setprio(0);
        }

        // ---- per-chunk epilogue: w = __expf, cos via v_fract+v_cos (revolutions) ----
        // (also hides the (c+1, ks=0) B prefetch issued above)
#pragma unroll
        for (int m = 0; m < 2; ++m)
#pragma unroll
            for (int n = 0; n < 2; ++n) {
                const int col = c * 256 + wc * 32 + n * 16 + lr;
                const float msq = musq[col], il2 = inv2s2[col], prv = phirev[col];
                f32x4 cc = accC[m][n], pp = accP[m][n];
#pragma unroll
                for (int rg = 0; rg < 4; ++rg) {
                    const int rowl = wr * 32 + m * 16 + lg * 4 + rg;
                    float dsq = fmaxf(sZsq[rowl] + msq - 2.0f * cc[rg], 0.f);
                    float w = __expf(-dsq * il2);
                    float ph = __builtin_fmaf(pp[rg], INV2PI, prv);
                    float r, cs;
                    asm("v_fract_f32 %0, %1" : "=v"(r) : "v"(ph));
                    asm("v_cos_f32 %0, %1" : "=v"(cs) : "v"(r));
                    out[(size_t)(rbase + rowl) * R_DIM + col] = w * cs;
                    rs[m * 4 + rg] += w;
                }
            }
    }

    // ---- block-local row sums -> normalize own 64x1024 tile ----
#pragma unroll
    for (int i = 0; i < 8; ++i) {
#pragma unroll
        for (int sh = 1; sh < 16; sh <<= 1) rs[i] += __shfl_xor(rs[i], sh, 64);
    }
    if (lr == 0) {
#pragma unroll
        for (int m = 0; m < 2; ++m)
#pragma unroll
            for (int rg = 0; rg < 4; ++rg)
                sRow[wc][wr * 32 + m * 16 + lg * 4 + rg] = rs[m * 4 + rg];
    }
    __syncthreads();
    if (tid < 64) {
        float s = 0.f;
#pragma unroll
        for (int w8 = 0; w8 < 8; ++w8) s += sRow[w8][tid];
        sInvN[tid] = 1.0f / fmaxf(s, 1e-6f);
    }
    __threadfence_block();
    __syncthreads();

    float4* obase = (float4*)(out + (size_t)rbase * R_DIM);
#pragma unroll 4
    for (int j = 0; j < 16; ++j) {
        const int idx = j * 1024 + tid;       // 0..16383 float4s
        const int row = idx >> 8, c4 = idx & 255;
        const float inv = sInvN[row];
        float4 v = obase[row * 256 + c4];
        v.x *= inv; v.y *= inv; v.z *= inv; v.w *= inv;
        obase[row * 256 + c4] = v;
    }
}

extern "C" void kernel_launch(void* const* d_in, const int* in_sizes, int n_in,
                              void* d_out, int out_size, void* d_ws, size_t ws_size,
                              hipStream_t stream) {
    const float* z    = (const float*)d_in[0];
    const float* mu   = (const float*)d_in[1];
    const float* Kmat = (const float*)d_in[2];
    const float* ls   = (const float*)d_in[3];
    const float* phi  = (const float*)d_in[4];
    float* out = (float*)d_out;
    float* ws = (float*)d_ws;
    float* zsq      = ws;                        // 16384
    float* musq     = ws + 16384;                // 1024
    float* i2s      = ws + 17408;                // 1024
    float* phirev   = ws + 18432;                // 1024
    _Float16* zf  = (_Float16*)(ws + 150528);    // 16384*512 halves (fragment order)
    _Float16* muf = zf + 8388608;                // 1024*512
    _Float16* kf  = muf + 524288;                // 1024*512
    const bool pre = ws_size >= 19476480ull;

    hipLaunchKernelGGL(gabor_prep, dim3(4096 + 256), dim3(256), 0, stream,
                       z, mu, ls, phi, zsq, musq, i2s, phirev);
    if (pre) {
        hipLaunchKernelGGL(gabor_split, dim3(2304), dim3(256), 0, stream,
                           z, mu, Kmat, zf, muf, kf);
        hipLaunchKernelGGL(gabor_main<true>, dim3(M_DIM / 64), dim3(1024), 0, stream,
                           z, mu, Kmat, zf, muf, kf, zsq, musq, i2s, phirev, out);
    } else {
        hipLaunchKernelGGL(gabor_main<false>, dim3(M_DIM / 64), dim3(1024), 0, stream,
                           z, mu, Kmat, zf, muf, kf, zsq, musq, i2s, phirev, out);
    }
}

// Round 12
// 91.888 us; speedup vs baseline: 1.2627x; 1.2556x over previous
//
#include <hip/hip_runtime.h>

// GaborBasis: out[b,t,r] = window_norm * cos(z·K[r] + phi[r]),
//   window = exp(-max(|z|^2+|mu_r|^2-2 z·mu_r,0)/(2 sigma_r^2)), normalized over r.
// fp16 hi/lo 3-term split MFMA (16x16x32); v_fract+v_cos epilogue.
// Round 12: round 10's 1-block/CU idea was right but 1024-thr blocks cap VGPR
// at 128 -> spill (VGPR=64, WRITE 229MB). Same idea, feasible form: 512 thr
// (8 waves), block = 64 rows x 1024 cols, grid 256 = 1 block/CU -> B traffic
// 2MB/CU (under the 24.8us MFMA pipe). Depth-2 B prefetch (load ks+2 into the
// slot freed by cluster ks) -> ~270cyc issue-to-use, covers L2 latency in-wave.

typedef _Float16 f16x8 __attribute__((ext_vector_type(8)));
typedef float f32x4 __attribute__((ext_vector_type(4)));

#define M_DIM 16384
#define R_DIM 1024
#define INV2PI 0.15915494309189535f

// ---------------- prep: z_sq[16384], mu_sq[1024], inv2s2[1024], phirev[1024] ----------------
__global__ void gabor_prep(const float* __restrict__ z, const float* __restrict__ mu,
                           const float* __restrict__ ls, const float* __restrict__ phi,
                           float* __restrict__ zsq, float* __restrict__ musq,
                           float* __restrict__ inv2s2, float* __restrict__ phirev) {
    const int lane = threadIdx.x & 63;
    const int wv = threadIdx.x >> 6;
    const int bid = blockIdx.x;
    if (bid < 4096) {
        const int row = bid * 4 + wv;
        float4 v = *(const float4*)(z + (size_t)row * 256 + lane * 4);
        float s = v.x * v.x + v.y * v.y + v.z * v.z + v.w * v.w;
#pragma unroll
        for (int sh = 1; sh < 64; sh <<= 1) s += __shfl_xor(s, sh, 64);
        if (lane == 0) zsq[row] = s;
    } else {
        const int row = (bid - 4096) * 4 + wv;
        float4 v = *(const float4*)(mu + (size_t)row * 256 + lane * 4);
        float s = v.x * v.x + v.y * v.y + v.z * v.z + v.w * v.w;
#pragma unroll
        for (int sh = 1; sh < 64; sh <<= 1) s += __shfl_xor(s, sh, 64);
        if (lane == 0) {
            musq[row] = s;
            float e = expf(ls[row]);
            inv2s2[row] = 1.0f / (2.0f * (e * e + 1e-8f));
            phirev[row] = phi[row] * INV2PI;
        }
    }
}

// ---------------- split: fp32 -> fp16 hi/lo in MFMA-fragment order ----------------
// Layout per matrix: [sub = row/16][ks = k/32][1024 halves]: hi at lane*8, lo at 512+lane*8,
// lane = (row&15) | ((k>>3 & 3)<<4). One thread = one (sub,ks,lane) = 8 fp32.
__global__ void gabor_split(const float* __restrict__ z, const float* __restrict__ mu,
                            const float* __restrict__ Kmat,
                            _Float16* __restrict__ zf, _Float16* __restrict__ muf,
                            _Float16* __restrict__ kf) {
    const int t = blockIdx.x * 256 + threadIdx.x;   // 0..589823
    const float* src; _Float16* dst; int item;
    if (t < 524288)      { item = t;          src = z;    dst = zf; }
    else if (t < 557056) { item = t - 524288; src = mu;   dst = muf; }
    else                 { item = t - 557056; src = Kmat; dst = kf; }
    const int sub = item >> 9, rem = item & 511;
    const int ks = rem >> 6, l = rem & 63;
    const int row = sub * 16 + (l & 15);
    const int k0 = ks * 32 + (l >> 4) * 8;
    const float* sp = src + (size_t)row * 256 + k0;
    float v[8];
    *(float4*)&v[0] = *(const float4*)(sp);
    *(float4*)&v[4] = *(const float4*)(sp + 4);
    f16x8 hi, lo;
#pragma unroll
    for (int j = 0; j < 8; ++j) {
        _Float16 h = (_Float16)v[j];
        hi[j] = h;
        lo[j] = (_Float16)(v[j] - (float)h);
    }
    _Float16* d = dst + (size_t)(sub * 8 + ks) * 1024;
    *(f16x8*)(d + l * 8) = hi;
    *(f16x8*)(d + 512 + l * 8) = lo;
}

// ---------------- main: 256 blocks x 512 thr (8 waves). Block = 64 rows x 1024 cols. ----------------
// Wave = 32 rows x 32 cols per chunk; 8 chunks of 128 cols. Barrier-free K loop.
template <bool PRE>
__global__ __launch_bounds__(512, 2) void gabor_main(
    const float* __restrict__ z, const float* __restrict__ mu, const float* __restrict__ Kmat,
    const _Float16* __restrict__ zf, const _Float16* __restrict__ muf, const _Float16* __restrict__ kf,
    const float* __restrict__ zsq, const float* __restrict__ musq,
    const float* __restrict__ inv2s2, const float* __restrict__ phirev,
    float* __restrict__ out) {
    __shared__ _Float16 sA[32768];      // [sub 0..3][ks 0..7][1024]: hi lane*8, lo 512+lane*8 (64KB)
    __shared__ float sZsq[64];
    __shared__ float sRow[4][64];
    __shared__ float sInvN[64];

    const int tid = threadIdx.x;
    const int bid = blockIdx.x;
    const int rbase = bid * 64;

    // ---- stage A panel (64 rows x 256 k, hi/lo) ONCE ----
    if constexpr (PRE) {
        const _Float16* zsrc = zf + (size_t)bid * 32768;            // 4 subs x 8 ks x 1024
#pragma unroll
        for (int j = 0; j < 8; ++j) {
            const int o = (j * 512 + tid) * 8;                      // 16B units, coalesced
            *(f16x8*)&sA[o] = *(const f16x8*)(zsrc + o);
        }
    } else {
#pragma unroll
        for (int j = 0; j < 4; ++j) {
            const int it = tid + j * 512;                            // 0..2047
            const int sub = it >> 9, rem = it & 511;
            const int ks = rem >> 6, l = rem & 63;
            const int row = rbase + sub * 16 + (l & 15);
            const float* sp = z + (size_t)row * 256 + ks * 32 + (l >> 4) * 8;
            float v[8];
            *(float4*)&v[0] = *(const float4*)(sp);
            *(float4*)&v[4] = *(const float4*)(sp + 4);
            f16x8 hi, lo;
#pragma unroll
            for (int q = 0; q < 8; ++q) {
                _Float16 h = (_Float16)v[q];
                hi[q] = h; lo[q] = (_Float16)(v[q] - (float)h);
            }
            const int o = (sub * 8 + ks) * 1024 + l * 8;
            *(f16x8*)&sA[o] = hi;
            *(f16x8*)&sA[o + 512] = lo;
        }
    }
    if (tid < 64) sZsq[tid] = zsq[rbase + tid];
    __syncthreads();                       // the ONLY barrier before the tail

    const int lane = tid & 63;
    const int wv = tid >> 6;               // 0..7
    const int wr = wv >> 2;                // 0..1 (32-row half)
    const int wc = wv & 3;                 // 0..3 (32-col slot within 128-col chunk)
    const int lr = lane & 15, lg = lane >> 4;

    float rs[8];
#pragma unroll
    for (int i = 0; i < 8; ++i) rs[i] = 0.f;

    // B register sets: [mu0H, mu0L, mu1H, mu1L, k0H, k0L, k1H, k1L] x2 (parity slots)
    f16x8 B[2][8];
    auto loadB = [&](int buf, int c, int ks) {
        if constexpr (PRE) {
            const size_t sb = (size_t)((c * 8 + wc * 2) * 8 + ks) * 1024 + lane * 8;
            const _Float16* mp = muf + sb;
            B[buf][0] = *(const f16x8*)(mp);
            B[buf][1] = *(const f16x8*)(mp + 512);
            B[buf][2] = *(const f16x8*)(mp + 8192);
            B[buf][3] = *(const f16x8*)(mp + 8192 + 512);
            const _Float16* kp = kf + sb;
            B[buf][4] = *(const f16x8*)(kp);
            B[buf][5] = *(const f16x8*)(kp + 512);
            B[buf][6] = *(const f16x8*)(kp + 8192);
            B[buf][7] = *(const f16x8*)(kp + 8192 + 512);
        } else {
#pragma unroll
            for (int n = 0; n < 2; ++n) {
                const int col = c * 128 + wc * 32 + n * 16 + lr;
                const int k0 = ks * 32 + lg * 8;
                float v[8];
                const float* sp = mu + (size_t)col * 256 + k0;
                *(float4*)&v[0] = *(const float4*)(sp);
                *(float4*)&v[4] = *(const float4*)(sp + 4);
#pragma unroll
                for (int q = 0; q < 8; ++q) {
                    _Float16 h = (_Float16)v[q];
                    B[buf][n * 2][q] = h; B[buf][n * 2 + 1][q] = (_Float16)(v[q] - (float)h);
                }
                const float* sp2 = Kmat + (size_t)col * 256 + k0;
                *(float4*)&v[0] = *(const float4*)(sp2);
                *(float4*)&v[4] = *(const float4*)(sp2 + 4);
#pragma unroll
                for (int q = 0; q < 8; ++q) {
                    _Float16 h = (_Float16)v[q];
                    B[buf][4 + n * 2][q] = h; B[buf][4 + n * 2 + 1][q] = (_Float16)(v[q] - (float)h);
                }
            }
        }
    };

    // depth-2 prologue
    loadB(0, 0, 0);
    loadB(1, 0, 1);

#pragma unroll 1
    for (int c = 0; c < 8; ++c) {
        f32x4 accC[2][2], accP[2][2];
#pragma unroll
        for (int m = 0; m < 2; ++m)
#pragma unroll
            for (int n = 0; n < 2; ++n) {
                accC[m][n] = (f32x4){0.f, 0.f, 0.f, 0.f};
                accP[m][n] = (f32x4){0.f, 0.f, 0.f, 0.f};
            }

#pragma unroll
        for (int ks = 0; ks < 8; ++ks) {
            const int cur = ks & 1;
            // A fragments from LDS (lane-linear, conflict-free)
            f16x8 aH[2], aL[2];
#pragma unroll
            for (int m = 0; m < 2; ++m) {
                const int o = ((wr * 2 + m) * 8 + ks) * 1024 + lane * 8;
                aH[m] = *(const f16x8*)&sA[o];
                aL[m] = *(const f16x8*)&sA[o + 512];
            }

            __builtin_amdgcn_s_setprio(1);
            // 8 independent 3-deep acc chains
#pragma unroll
            for (int m = 0; m < 2; ++m)
#pragma unroll
                for (int n = 0; n < 2; ++n)
                    accC[m][n] = __builtin_amdgcn_mfma_f32_16x16x32_f16(aH[m], B[cur][n * 2], accC[m][n], 0, 0, 0);
#pragma unroll
            for (int m = 0; m < 2; ++m)
#pragma unroll
                for (int n = 0; n < 2; ++n)
                    accP[m][n] = __builtin_amdgcn_mfma_f32_16x16x32_f16(aH[m], B[cur][4 + n * 2], accP[m][n], 0, 0, 0);
#pragma unroll
            for (int m = 0; m < 2; ++m)
#pragma unroll
                for (int n = 0; n < 2; ++n)
                    accC[m][n] = __builtin_amdgcn_mfma_f32_16x16x32_f16(aH[m], B[cur][n * 2 + 1], accC[m][n], 0, 0, 0);
#pragma unroll
            for (int m = 0; m < 2; ++m)
#pragma unroll
                for (int n = 0; n < 2; ++n)
                    accP[m][n] = __builtin_amdgcn_mfma_f32_16x16x32_f16(aH[m], B[cur][4 + n * 2 + 1], accP[m][n], 0, 0, 0);
#pragma unroll
            for (int m = 0; m < 2; ++m)
#pragma unroll
                for (int n = 0; n < 2; ++n)
                    accC[m][n] = __builtin_amdgcn_mfma_f32_16x16x32_f16(aL[m], B[cur][n * 2], accC[m][n], 0, 0, 0);
#pragma unroll
            for (int m = 0; m < 2; ++m)
#pragma unroll
                for (int n = 0; n < 2; ++n)
                    accP[m][n] = __builtin_amdgcn_mfma_f32_16x16x32_f16(aL[m], B[cur][4 + n * 2], accP[m][n], 0, 0, 0);
            __builtin_amdgcn_s_setprio(0);

            // depth-2 rolling prefetch into the slot the cluster just freed:
            // target global step = (c, ks+2); crosses into next chunk cleanly.
            const bool have = (ks + 2 < 8) || (c < 7);
            if (have) {
                const int tc = (ks + 2 < 8) ? c : c + 1;
                const int tks = (ks + 2) & 7;
                loadB(cur, tc, tks);
            }
            __builtin_amdgcn_sched_barrier(0);
        }

        // ---- per-chunk epilogue: w = __expf, cos via v_fract+v_cos (revolutions) ----
        // (~320 cyc VALU; also covers the 2 in-flight B loads for the next chunk)
#pragma unroll
        for (int m = 0; m < 2; ++m)
#pragma unroll
            for (int n = 0; n < 2; ++n) {
                const int col = c * 128 + wc * 32 + n * 16 + lr;
                const float msq = musq[col], il2 = inv2s2[col], prv = phirev[col];
                f32x4 cc = accC[m][n], pp = accP[m][n];
#pragma unroll
                for (int rg = 0; rg < 4; ++rg) {
                    const int rowl = wr * 32 + m * 16 + lg * 4 + rg;
                    float dsq = fmaxf(sZsq[rowl] + msq - 2.0f * cc[rg], 0.f);
                    float w = __expf(-dsq * il2);
                    float ph = __builtin_fmaf(pp[rg], INV2PI, prv);
                    float r, cs;
                    asm("v_fract_f32 %0, %1" : "=v"(r) : "v"(ph));
                    asm("v_cos_f32 %0, %1" : "=v"(cs) : "v"(r));
                    out[(size_t)(rbase + rowl) * R_DIM + col] = w * cs;
                    rs[m * 4 + rg] += w;
                }
            }
    }

    // ---- block-local row sums -> normalize own 64x1024 tile ----
#pragma unroll
    for (int i = 0; i < 8; ++i) {
#pragma unroll
        for (int sh = 1; sh < 16; sh <<= 1) rs[i] += __shfl_xor(rs[i], sh, 64);
    }
    if (lr == 0) {
#pragma unroll
        for (int m = 0; m < 2; ++m)
#pragma unroll
            for (int rg = 0; rg < 4; ++rg)
                sRow[wc][wr * 32 + m * 16 + lg * 4 + rg] = rs[m * 4 + rg];
    }
    __syncthreads();
    if (tid < 64) {
        float s = sRow[0][tid] + sRow[1][tid] + sRow[2][tid] + sRow[3][tid];
        sInvN[tid] = 1.0f / fmaxf(s, 1e-6f);
    }
    __threadfence_block();
    __syncthreads();

    float4* obase = (float4*)(out + (size_t)rbase * R_DIM);
#pragma unroll 4
    for (int j = 0; j < 32; ++j) {
        const int idx = j * 512 + tid;        // 0..16383 float4s
        const int row = idx >> 8, c4 = idx & 255;
        const float inv = sInvN[row];
        float4 v = obase[row * 256 + c4];
        v.x *= inv; v.y *= inv; v.z *= inv; v.w *= inv;
        obase[row * 256 + c4] = v;
    }
}

extern "C" void kernel_launch(void* const* d_in, const int* in_sizes, int n_in,
                              void* d_out, int out_size, void* d_ws, size_t ws_size,
                              hipStream_t stream) {
    const float* z    = (const float*)d_in[0];
    const float* mu   = (const float*)d_in[1];
    const float* Kmat = (const float*)d_in[2];
    const float* ls   = (const float*)d_in[3];
    const float* phi  = (const float*)d_in[4];
    float* out = (float*)d_out;
    float* ws = (float*)d_ws;
    float* zsq      = ws;                        // 16384
    float* musq     = ws + 16384;                // 1024
    float* i2s      = ws + 17408;                // 1024
    float* phirev   = ws + 18432;                // 1024
    _Float16* zf  = (_Float16*)(ws + 150528);    // 16384*512 halves (fragment order)
    _Float16* muf = zf + 8388608;                // 1024*512
    _Float16* kf  = muf + 524288;                // 1024*512
    const bool pre = ws_size >= 19476480ull;

    hipLaunchKernelGGL(gabor_prep, dim3(4096 + 256), dim3(256), 0, stream,
                       z, mu, ls, phi, zsq, musq, i2s, phirev);
    if (pre) {
        hipLaunchKernelGGL(gabor_split, dim3(2304), dim3(256), 0, stream,
                           z, mu, Kmat, zf, muf, kf);
        hipLaunchKernelGGL(gabor_main<true>, dim3(M_DIM / 64), dim3(512), 0, stream,
                           z, mu, Kmat, zf, muf, kf, zsq, musq, i2s, phirev, out);
    } else {
        hipLaunchKernelGGL(gabor_main<false>, dim3(M_DIM / 64), dim3(512), 0, stream,
                           z, mu, Kmat, zf, muf, kf, zsq, musq, i2s, phirev, out);
    }
}

// Round 13
// 82.813 us; speedup vs baseline: 1.4010x; 1.1096x over previous
//
#include <hip/hip_runtime.h>

// GaborBasis: out[b,t,r] = window_norm * cos(z·K[r] + phi[r]),
//   window = exp(-max(|z|^2+|mu_r|^2-2 z·mu_r,0)/(2 sigma_r^2)), normalized over r.
// fp16 hi/lo 3-term split MFMA (16x16x32); v_fract+v_cos epilogue.
// Round 13: six designs converged at 71-85us / ~26% MfmaUtil with all pipes
// <=30% -> per-iteration latency amortized over too-small (24-MFMA) clusters,
// plus B loads duplicated by row-paired waves. Now wave = 64 rows x 128 cols
// (disjoint cols per wave -> 2MB/CU unique B, no dup), 48-MFMA clusters
// (932 cyc between wait points, 2x amortization, half the iterations).

typedef _Float16 f16x8 __attribute__((ext_vector_type(8)));
typedef float f32x4 __attribute__((ext_vector_type(4)));

#define M_DIM 16384
#define R_DIM 1024
#define INV2PI 0.15915494309189535f

// ---------------- prep: z_sq[16384], mu_sq[1024], inv2s2[1024], phirev[1024] ----------------
__global__ void gabor_prep(const float* __restrict__ z, const float* __restrict__ mu,
                           const float* __restrict__ ls, const float* __restrict__ phi,
                           float* __restrict__ zsq, float* __restrict__ musq,
                           float* __restrict__ inv2s2, float* __restrict__ phirev) {
    const int lane = threadIdx.x & 63;
    const int wv = threadIdx.x >> 6;
    const int bid = blockIdx.x;
    if (bid < 4096) {
        const int row = bid * 4 + wv;
        float4 v = *(const float4*)(z + (size_t)row * 256 + lane * 4);
        float s = v.x * v.x + v.y * v.y + v.z * v.z + v.w * v.w;
#pragma unroll
        for (int sh = 1; sh < 64; sh <<= 1) s += __shfl_xor(s, sh, 64);
        if (lane == 0) zsq[row] = s;
    } else {
        const int row = (bid - 4096) * 4 + wv;
        float4 v = *(const float4*)(mu + (size_t)row * 256 + lane * 4);
        float s = v.x * v.x + v.y * v.y + v.z * v.z + v.w * v.w;
#pragma unroll
        for (int sh = 1; sh < 64; sh <<= 1) s += __shfl_xor(s, sh, 64);
        if (lane == 0) {
            musq[row] = s;
            float e = expf(ls[row]);
            inv2s2[row] = 1.0f / (2.0f * (e * e + 1e-8f));
            phirev[row] = phi[row] * INV2PI;
        }
    }
}

// ---------------- split: fp32 -> fp16 hi/lo in MFMA-fragment order ----------------
// Layout per matrix: [sub = row/16][ks = k/32][1024 halves]: hi at lane*8, lo at 512+lane*8,
// lane = (row&15) | ((k>>3 & 3)<<4). One thread = one (sub,ks,lane) = 8 fp32.
__global__ void gabor_split(const float* __restrict__ z, const float* __restrict__ mu,
                            const float* __restrict__ Kmat,
                            _Float16* __restrict__ zf, _Float16* __restrict__ muf,
                            _Float16* __restrict__ kf) {
    const int t = blockIdx.x * 256 + threadIdx.x;   // 0..589823
    const float* src; _Float16* dst; int item;
    if (t < 524288)      { item = t;          src = z;    dst = zf; }
    else if (t < 557056) { item = t - 524288; src = mu;   dst = muf; }
    else                 { item = t - 557056; src = Kmat; dst = kf; }
    const int sub = item >> 9, rem = item & 511;
    const int ks = rem >> 6, l = rem & 63;
    const int row = sub * 16 + (l & 15);
    const int k0 = ks * 32 + (l >> 4) * 8;
    const float* sp = src + (size_t)row * 256 + k0;
    float v[8];
    *(float4*)&v[0] = *(const float4*)(sp);
    *(float4*)&v[4] = *(const float4*)(sp + 4);
    f16x8 hi, lo;
#pragma unroll
    for (int j = 0; j < 8; ++j) {
        _Float16 h = (_Float16)v[j];
        hi[j] = h;
        lo[j] = (_Float16)(v[j] - (float)h);
    }
    _Float16* d = dst + (size_t)(sub * 8 + ks) * 1024;
    *(f16x8*)(d + l * 8) = hi;
    *(f16x8*)(d + 512 + l * 8) = lo;
}

// ---------------- main: 256 blocks x 512 thr (8 waves). Block = 64 rows x 1024 cols. ----------------
// Wave = all 64 rows x disjoint 128-col slice; 4 chunks of 32 cols; 48-MFMA clusters.
template <bool PRE>
__global__ __launch_bounds__(512, 2) void gabor_main(
    const float* __restrict__ z, const float* __restrict__ mu, const float* __restrict__ Kmat,
    const _Float16* __restrict__ zf, const _Float16* __restrict__ muf, const _Float16* __restrict__ kf,
    const float* __restrict__ zsq, const float* __restrict__ musq,
    const float* __restrict__ inv2s2, const float* __restrict__ phirev,
    float* __restrict__ out) {
    __shared__ _Float16 sA[32768];      // [sub 0..3][ks 0..7][1024]: hi lane*8, lo 512+lane*8 (64KB)
    __shared__ float sZsq[64];
    __shared__ float sRow[8][64];
    __shared__ float sInvN[64];

    const int tid = threadIdx.x;
    const int bid = blockIdx.x;
    const int rbase = bid * 64;

    // ---- stage A panel (64 rows x 256 k, hi/lo) ONCE ----
    if constexpr (PRE) {
        const _Float16* zsrc = zf + (size_t)bid * 32768;            // 4 subs x 8 ks x 1024
#pragma unroll
        for (int j = 0; j < 8; ++j) {
            const int o = (j * 512 + tid) * 8;                      // 16B units, coalesced
            *(f16x8*)&sA[o] = *(const f16x8*)(zsrc + o);
        }
    } else {
#pragma unroll
        for (int j = 0; j < 4; ++j) {
            const int it = tid + j * 512;                            // 0..2047
            const int sub = it >> 9, rem = it & 511;
            const int ks = rem >> 6, l = rem & 63;
            const int row = rbase + sub * 16 + (l & 15);
            const float* sp = z + (size_t)row * 256 + ks * 32 + (l >> 4) * 8;
            float v[8];
            *(float4*)&v[0] = *(const float4*)(sp);
            *(float4*)&v[4] = *(const float4*)(sp + 4);
            f16x8 hi, lo;
#pragma unroll
            for (int q = 0; q < 8; ++q) {
                _Float16 h = (_Float16)v[q];
                hi[q] = h; lo[q] = (_Float16)(v[q] - (float)h);
            }
            const int o = (sub * 8 + ks) * 1024 + l * 8;
            *(f16x8*)&sA[o] = hi;
            *(f16x8*)&sA[o + 512] = lo;
        }
    }
    if (tid < 64) sZsq[tid] = zsq[rbase + tid];
    __syncthreads();                       // the ONLY barrier before the tail

    const int lane = tid & 63;
    const int wc = tid >> 6;               // 0..7 : this wave's 128-col slice (disjoint)
    const int lr = lane & 15, lg = lane >> 4;

    float rs[16];
#pragma unroll
    for (int i = 0; i < 16; ++i) rs[i] = 0.f;

    // B register sets: [mu0H, mu0L, mu1H, mu1L, k0H, k0L, k1H, k1L] x2 (ping-pong)
    f16x8 B[2][8];
    auto loadB = [&](int buf, int cc, int ks) {
        if constexpr (PRE) {
            // col sub-block = wc*8 + cc*2 (+1 for n=1)
            const size_t sb = (size_t)((wc * 8 + cc * 2) * 8 + ks) * 1024 + lane * 8;
            const _Float16* mp = muf + sb;
            B[buf][0] = *(const f16x8*)(mp);
            B[buf][1] = *(const f16x8*)(mp + 512);
            B[buf][2] = *(const f16x8*)(mp + 8192);
            B[buf][3] = *(const f16x8*)(mp + 8192 + 512);
            const _Float16* kp = kf + sb;
            B[buf][4] = *(const f16x8*)(kp);
            B[buf][5] = *(const f16x8*)(kp + 512);
            B[buf][6] = *(const f16x8*)(kp + 8192);
            B[buf][7] = *(const f16x8*)(kp + 8192 + 512);
        } else {
#pragma unroll
            for (int n = 0; n < 2; ++n) {
                const int col = wc * 128 + cc * 32 + n * 16 + lr;
                const int k0 = ks * 32 + lg * 8;
                float v[8];
                const float* sp = mu + (size_t)col * 256 + k0;
                *(float4*)&v[0] = *(const float4*)(sp);
                *(float4*)&v[4] = *(const float4*)(sp + 4);
#pragma unroll
                for (int q = 0; q < 8; ++q) {
                    _Float16 h = (_Float16)v[q];
                    B[buf][n * 2][q] = h; B[buf][n * 2 + 1][q] = (_Float16)(v[q] - (float)h);
                }
                const float* sp2 = Kmat + (size_t)col * 256 + k0;
                *(float4*)&v[0] = *(const float4*)(sp2);
                *(float4*)&v[4] = *(const float4*)(sp2 + 4);
#pragma unroll
                for (int q = 0; q < 8; ++q) {
                    _Float16 h = (_Float16)v[q];
                    B[buf][4 + n * 2][q] = h; B[buf][4 + n * 2 + 1][q] = (_Float16)(v[q] - (float)h);
                }
            }
        }
    };

    loadB(0, 0, 0);

#pragma unroll 1
    for (int cc = 0; cc < 4; ++cc) {
        f32x4 accC[4][2], accP[4][2];
#pragma unroll
        for (int m = 0; m < 4; ++m)
#pragma unroll
            for (int n = 0; n < 2; ++n) {
                accC[m][n] = (f32x4){0.f, 0.f, 0.f, 0.f};
                accP[m][n] = (f32x4){0.f, 0.f, 0.f, 0.f};
            }

#pragma unroll
        for (int ks = 0; ks < 8; ++ks) {
            const int cur = ks & 1;
            const int nxt = cur ^ 1;
            // A fragments from LDS: all 4 row-subs (lane-linear, conflict-free)
            f16x8 aH[4], aL[4];
#pragma unroll
            for (int m = 0; m < 4; ++m) {
                const int o = (m * 8 + ks) * 1024 + lane * 8;
                aH[m] = *(const f16x8*)&sA[o];
                aL[m] = *(const f16x8*)&sA[o + 512];
            }
            // ping-pong B prefetch: issue->use distance = one 48-MFMA cluster
            if (ks < 7) loadB(nxt, cc, ks + 1);
            else if (cc < 3) loadB(nxt, cc + 1, 0);   // also covered by chunk epilogue
            __builtin_amdgcn_sched_barrier(0);

            __builtin_amdgcn_s_setprio(1);
            // 16 independent acc chains, 48 MFMA
#pragma unroll
            for (int m = 0; m < 4; ++m)
#pragma unroll
                for (int n = 0; n < 2; ++n)
                    accC[m][n] = __builtin_amdgcn_mfma_f32_16x16x32_f16(aH[m], B[cur][n * 2], accC[m][n], 0, 0, 0);
#pragma unroll
            for (int m = 0; m < 4; ++m)
#pragma unroll
                for (int n = 0; n < 2; ++n)
                    accP[m][n] = __builtin_amdgcn_mfma_f32_16x16x32_f16(aH[m], B[cur][4 + n * 2], accP[m][n], 0, 0, 0);
#pragma unroll
            for (int m = 0; m < 4; ++m)
#pragma unroll
                for (int n = 0; n < 2; ++n)
                    accC[m][n] = __builtin_amdgcn_mfma_f32_16x16x32_f16(aH[m], B[cur][n * 2 + 1], accC[m][n], 0, 0, 0);
#pragma unroll
            for (int m = 0; m < 4; ++m)
#pragma unroll
                for (int n = 0; n < 2; ++n)
                    accP[m][n] = __builtin_amdgcn_mfma_f32_16x16x32_f16(aH[m], B[cur][4 + n * 2 + 1], accP[m][n], 0, 0, 0);
#pragma unroll
            for (int m = 0; m < 4; ++m)
#pragma unroll
                for (int n = 0; n < 2; ++n)
                    accC[m][n] = __builtin_amdgcn_mfma_f32_16x16x32_f16(aL[m], B[cur][n * 2], accC[m][n], 0, 0, 0);
#pragma unroll
            for (int m = 0; m < 4; ++m)
#pragma unroll
                for (int n = 0; n < 2; ++n)
                    accP[m][n] = __builtin_amdgcn_mfma_f32_16x16x32_f16(aL[m], B[cur][4 + n * 2], accP[m][n], 0, 0, 0);
            __builtin_amdgcn_s_setprio(0);
        }

        // ---- per-chunk epilogue: w = __expf, cos via v_fract+v_cos (revolutions) ----
#pragma unroll
        for (int m = 0; m < 4; ++m)
#pragma unroll
            for (int n = 0; n < 2; ++n) {
                const int col = wc * 128 + cc * 32 + n * 16 + lr;
                const float msq = musq[col], il2 = inv2s2[col], prv = phirev[col];
                f32x4 ccv = accC[m][n], pp = accP[m][n];
#pragma unroll
                for (int rg = 0; rg < 4; ++rg) {
                    const int rowl = m * 16 + lg * 4 + rg;
                    float dsq = fmaxf(sZsq[rowl] + msq - 2.0f * ccv[rg], 0.f);
                    float w = __expf(-dsq * il2);
                    float ph = __builtin_fmaf(pp[rg], INV2PI, prv);
                    float r, cs;
                    asm("v_fract_f32 %0, %1" : "=v"(r) : "v"(ph));
                    asm("v_cos_f32 %0, %1" : "=v"(cs) : "v"(r));
                    out[(size_t)(rbase + rowl) * R_DIM + col] = w * cs;
                    rs[m * 4 + rg] += w;
                }
            }
    }

    // ---- block-local row sums -> normalize own 64x1024 tile ----
#pragma unroll
    for (int i = 0; i < 16; ++i) {
#pragma unroll
        for (int sh = 1; sh < 16; sh <<= 1) rs[i] += __shfl_xor(rs[i], sh, 64);
    }
    if (lr == 0) {
#pragma unroll
        for (int m = 0; m < 4; ++m)
#pragma unroll
            for (int rg = 0; rg < 4; ++rg)
                sRow[wc][m * 16 + lg * 4 + rg] = rs[m * 4 + rg];
    }
    __syncthreads();
    if (tid < 64) {
        float s = 0.f;
#pragma unroll
        for (int w8 = 0; w8 < 8; ++w8) s += sRow[w8][tid];
        sInvN[tid] = 1.0f / fmaxf(s, 1e-6f);
    }
    __threadfence_block();
    __syncthreads();

    float4* obase = (float4*)(out + (size_t)rbase * R_DIM);
#pragma unroll 4
    for (int j = 0; j < 32; ++j) {
        const int idx = j * 512 + tid;        // 0..16383 float4s
        const int row = idx >> 8, c4 = idx & 255;
        const float inv = sInvN[row];
        float4 v = obase[row * 256 + c4];
        v.x *= inv; v.y *= inv; v.z *= inv; v.w *= inv;
        obase[row * 256 + c4] = v;
    }
}

extern "C" void kernel_launch(void* const* d_in, const int* in_sizes, int n_in,
                              void* d_out, int out_size, void* d_ws, size_t ws_size,
                              hipStream_t stream) {
    const float* z    = (const float*)d_in[0];
    const float* mu   = (const float*)d_in[1];
    const float* Kmat = (const float*)d_in[2];
    const float* ls   = (const float*)d_in[3];
    const float* phi  = (const float*)d_in[4];
    float* out = (float*)d_out;
    float* ws = (float*)d_ws;
    float* zsq      = ws;                        // 16384
    float* musq     = ws + 16384;                // 1024
    float* i2s      = ws + 17408;                // 1024
    float* phirev   = ws + 18432;                // 1024
    _Float16* zf  = (_Float16*)(ws + 150528);    // 16384*512 halves (fragment order)
    _Float16* muf = zf + 8388608;                // 1024*512
    _Float16* kf  = muf + 524288;                // 1024*512
    const bool pre = ws_size >= 19476480ull;

    hipLaunchKernelGGL(gabor_prep, dim3(4096 + 256), dim3(256), 0, stream,
                       z, mu, ls, phi, zsq, musq, i2s, phirev);
    if (pre) {
        hipLaunchKernelGGL(gabor_split, dim3(2304), dim3(256), 0, stream,
                           z, mu, Kmat, zf, muf, kf);
        hipLaunchKernelGGL(gabor_main<true>, dim3(M_DIM / 64), dim3(512), 0, stream,
                           z, mu, Kmat, zf, muf, kf, zsq, musq, i2s, phirev, out);
    } else {
        hipLaunchKernelGGL(gabor_main<false>, dim3(M_DIM / 64), dim3(512), 0, stream,
                           z, mu, Kmat, zf, muf, kf, zsq, musq, i2s, phirev, out);
    }
}